// Round 4
// baseline (133.455 us; speedup 1.0000x reference)
//
#include <hip/hip_runtime.h>

// Problem constants (fixed by setup_inputs: B=64, PER=512, N_COMPOUND=112)
constexpr int PERN = 512;
constexpr int NCMP = 112;
constexpr int BATCHES = 64;
constexpr float INTRA_CUT = 1.6f;   // 8.0 / 5.0
constexpr float INTER_CUT = 2.0f;   // 10.0 / 5.0
constexpr int ROWS_PER_BLOCK = 16;  // 32 blocks per batch

typedef float f32x4 __attribute__((ext_vector_type(4)));  // builtin vec for nontemporal_store

// __launch_bounds__(256, 8): 8 waves/EU -> compiler caps VGPR at 64 so the
// CU holds the full 32 waves (store-latency hiding for the 201MB stream).
__global__ __launch_bounds__(256, 8) void pair_mask_kernel(
    const float* __restrict__ X, float* __restrict__ out)
{
    // Swizzled point tile for one batch: slot = p ^ ((p>>3)&7) spreads the
    // 128B-strided per-lane float4 reads across all 32 banks (<=2-way, free).
    __shared__ float4 pt[PERN];

    const int tid = threadIdx.x;
    const int blk = blockIdx.x;
    const int b = blk / (PERN / ROWS_PER_BLOCK);
    const int row0 = (blk % (PERN / ROWS_PER_BLOCK)) * ROWS_PER_BLOCK;

    // Stage this batch's 512 points (1536 floats) into LDS, transposed to
    // swizzled float4 slots. Coalesced global reads; LDS writes scattered (cheap).
    const float* Xb = X + (size_t)b * PERN * 3;
    for (int f = tid; f < PERN * 3; f += 256) {
        int p = f / 3;
        int c = f - p * 3;
        int slot = p ^ ((p >> 3) & 7);
        reinterpret_cast<float*>(&pt[slot])[c] = Xb[f];
    }
    __syncthreads();

    const int lane = tid & 63;   // j-group within row
    const int sub = tid >> 6;    // which of 4 rows this pass
    const int j0 = lane << 3;    // 8 consecutive j per lane
    const size_t NP = (size_t)BATCHES * PERN * PERN;  // elements per plane

    for (int pass = 0; pass < ROWS_PER_BLOCK / 4; ++pass) {
        const int li = row0 + pass * 4 + sub;          // local row index
        const int sloti = li ^ ((li >> 3) & 7);
        const float4 pi = pt[sloti];
        const bool rg = (li == 0) | (li == NCMP);      // row is_global
        const int  sr = (li >= NCMP);                  // row segment
        const size_t base = ((size_t)(b * PERN + li)) * PERN + (size_t)j0;
        float* o0 = out + base;
        float* o1 = out + NP + base;
        float* o2 = out + 2 * NP + base;

        // Two 4-wide halves: store each float4 as soon as assembled to keep
        // the live register set small (target <=64 VGPR).
#pragma unroll
        for (int half = 0; half < 2; ++half) {
            f32x4 cc, ii, mm;
#pragma unroll
            for (int k = 0; k < 4; ++k) {
                const int j = j0 + half * 4 + k;
                const int slot = j ^ ((j >> 3) & 7);
                const float4 pj = pt[slot];
                const float dx = pi.x - pj.x;
                const float dy = pi.y - pj.y;
                const float dz = pi.z - pj.z;
                const float d2 = dx * dx + dy * dy + dz * dz;
                const bool valid = (j != li);
                const bool fin = valid & (d2 > 0.0f);      // dist finite in ref
                const float dist = __builtin_amdgcn_sqrtf(d2);
                const bool cgl = (j == 0) | (j == NCMP);   // col is_global (raw)
                const bool cg = cgl & valid;
                const bool notg = !(rg | cg);
                const int  sj = (j >= NCMP);
                const bool same = valid & (sr == sj);
                const bool ctxr  = same & (sr == 1) & notg & fin & (dist <= INTRA_CUT);
                const bool inter = valid & (sr != sj) & notg & fin & (dist <= INTER_CUT);
                const bool gnorm = same & (!notg);
                const bool gg    = valid & rg & cgl;
                const bool ctx   = ctxr | gnorm | gg;
                cc[k] = ctx ? 1.0f : 0.0f;
                ii[k] = inter ? 1.0f : 0.0f;
                mm[k] = ((ctx | inter) & fin) ? dist : 0.0f;
            }
            __builtin_nontemporal_store(cc, reinterpret_cast<f32x4*>(o0 + half * 4));
            __builtin_nontemporal_store(ii, reinterpret_cast<f32x4*>(o1 + half * 4));
            __builtin_nontemporal_store(mm, reinterpret_cast<f32x4*>(o2 + half * 4));
        }
    }
}

extern "C" void kernel_launch(void* const* d_in, const int* in_sizes, int n_in,
                              void* d_out, int out_size, void* d_ws, size_t ws_size,
                              hipStream_t stream) {
    const float* X = (const float*)d_in[0];
    float* out = (float*)d_out;
    const int grid = BATCHES * (PERN / ROWS_PER_BLOCK);  // 2048 blocks
    pair_mask_kernel<<<grid, 256, 0, stream>>>(X, out);
}

// Round 5
// 43.238 us; speedup vs baseline: 3.0865x; 3.0865x over previous
//
#include <hip/hip_runtime.h>

// Problem constants (fixed by setup_inputs: B=64, PER=512, N_COMPOUND=112)
constexpr int PERN = 512;
constexpr int NCMP = 112;
constexpr int BATCHES = 64;
constexpr float INTRA_CUT = 1.6f;   // 8.0 / 5.0
constexpr float INTER_CUT = 2.0f;   // 10.0 / 5.0
constexpr int ROWS_PER_BLOCK = 16;  // 32 blocks per batch

typedef float f32x4 __attribute__((ext_vector_type(4)));

// 8 waves/EU -> VGPR capped at 64 -> full 32 waves/CU for store-latency hiding.
__global__ __launch_bounds__(256, 8) void pair_mask_kernel(
    const float* __restrict__ X, float* __restrict__ out)
{
    // Swizzled point tile: slot = p ^ ((p>>3)&7) spreads per-lane float4 reads
    // across banks.
    __shared__ float4 pt[PERN];

    const int tid = threadIdx.x;
    const int blk = blockIdx.x;
    const int b = blk / (PERN / ROWS_PER_BLOCK);
    const int row0 = (blk % (PERN / ROWS_PER_BLOCK)) * ROWS_PER_BLOCK;

    // Stage this batch's 512 points into swizzled float4 slots.
    const float* Xb = X + (size_t)b * PERN * 3;
    for (int f = tid; f < PERN * 3; f += 256) {
        int p = f / 3;
        int c = f - p * 3;
        int slot = p ^ ((p >> 3) & 7);
        reinterpret_cast<float*>(&pt[slot])[c] = Xb[f];
    }
    __syncthreads();

    const int lane = tid & 63;   // lane within wave
    const int sub = tid >> 6;    // which of 4 rows this pass
    const size_t NP = (size_t)BATCHES * PERN * PERN;  // elements per plane

    for (int pass = 0; pass < ROWS_PER_BLOCK / 4; ++pass) {
        const int li = row0 + pass * 4 + sub;          // local row index
        const int sloti = li ^ ((li >> 3) & 7);
        const float4 pi = pt[sloti];
        const bool rg = (li == 0) | (li == NCMP);      // row is_global
        const int  sr = (li >= NCMP);                  // row segment
        float* orow = out + (size_t)(b * PERN + li) * PERN;

        // Two chunks: lane owns j = c*256 + 4*lane + k. Each f32x4 store is
        // wave-contiguous (64 lanes x 16B = 1KB aligned burst -> full 64B
        // lines for the nontemporal path; no write amplification).
#pragma unroll
        for (int c = 0; c < 2; ++c) {
            const int jbase = c * 256 + (lane << 2);
            f32x4 cc, ii, mm;
#pragma unroll
            for (int k = 0; k < 4; ++k) {
                const int j = jbase + k;
                const int slot = j ^ ((j >> 3) & 7);
                const float4 pj = pt[slot];
                const float dx = pi.x - pj.x;
                const float dy = pi.y - pj.y;
                const float dz = pi.z - pj.z;
                const float d2 = dx * dx + dy * dy + dz * dz;
                const bool valid = (j != li);
                const bool fin = valid & (d2 > 0.0f);      // dist finite in ref
                const float dist = __builtin_amdgcn_sqrtf(d2);
                const bool cgl = (j == 0) | (j == NCMP);   // col is_global (raw)
                const bool cg = cgl & valid;
                const bool notg = !(rg | cg);
                const int  sj = (j >= NCMP);
                const bool same = valid & (sr == sj);
                const bool ctxr  = same & (sr == 1) & notg & fin & (dist <= INTRA_CUT);
                const bool inter = valid & (sr != sj) & notg & fin & (dist <= INTER_CUT);
                const bool gnorm = same & (!notg);
                const bool gg    = valid & rg & cgl;
                const bool ctx   = ctxr | gnorm | gg;
                cc[k] = ctx ? 1.0f : 0.0f;
                ii[k] = inter ? 1.0f : 0.0f;
                mm[k] = ((ctx | inter) & fin) ? dist : 0.0f;
            }
            __builtin_nontemporal_store(cc, reinterpret_cast<f32x4*>(orow + jbase));
            __builtin_nontemporal_store(ii, reinterpret_cast<f32x4*>(orow + NP + jbase));
            __builtin_nontemporal_store(mm, reinterpret_cast<f32x4*>(orow + 2 * NP + jbase));
        }
    }
}

extern "C" void kernel_launch(void* const* d_in, const int* in_sizes, int n_in,
                              void* d_out, int out_size, void* d_ws, size_t ws_size,
                              hipStream_t stream) {
    const float* X = (const float*)d_in[0];
    float* out = (float*)d_out;
    const int grid = BATCHES * (PERN / ROWS_PER_BLOCK);  // 2048 blocks
    pair_mask_kernel<<<grid, 256, 0, stream>>>(X, out);
}

// Round 6
// 36.729 us; speedup vs baseline: 3.6335x; 1.1772x over previous
//
#include <hip/hip_runtime.h>

// Problem constants (fixed by setup_inputs: B=64, PER=512, N_COMPOUND=112)
constexpr int PERN = 512;
constexpr int NCMP = 112;
constexpr int BATCHES = 64;
constexpr float INTRA_CUT = 1.6f;   // 8.0 / 5.0
constexpr float INTER_CUT = 2.0f;   // 10.0 / 5.0
constexpr int ROWS_PER_BLOCK = 16;  // 32 blocks per batch

typedef float f32x4 __attribute__((ext_vector_type(4)));

// 8 waves/EU -> VGPR capped at 64 -> full 32 waves/CU for store-latency hiding.
__global__ __launch_bounds__(256, 8) void pair_mask_kernel(
    const float* __restrict__ X, float* __restrict__ out)
{
    // Swizzled point tile: slot = p ^ ((p>>3)&7) spreads per-lane float4 reads
    // across banks (slot&7 unique within each 8-lane octet -> <=2-way, free).
    __shared__ float4 pt[PERN];

    const int tid = threadIdx.x;
    const int blk = blockIdx.x;
    const int b = blk / (PERN / ROWS_PER_BLOCK);
    const int row0 = (blk % (PERN / ROWS_PER_BLOCK)) * ROWS_PER_BLOCK;

    // Stage this batch's 512 points into swizzled float4 slots.
    const float* Xb = X + (size_t)b * PERN * 3;
    for (int f = tid; f < PERN * 3; f += 256) {
        int p = f / 3;
        int c = f - p * 3;
        int slot = p ^ ((p >> 3) & 7);
        reinterpret_cast<float*>(&pt[slot])[c] = Xb[f];
    }
    __syncthreads();

    const int lane = tid & 63;   // lane within wave
    const int sub = tid >> 6;    // which of 4 rows this pass
    const size_t NP = (size_t)BATCHES * PERN * PERN;  // elements per plane

    for (int pass = 0; pass < ROWS_PER_BLOCK / 4; ++pass) {
        const int li = row0 + pass * 4 + sub;          // local row index
        const int sloti = li ^ ((li >> 3) & 7);
        const float4 pi = pt[sloti];                   // wave-broadcast read
        const bool rg = (li == 0) | (li == NCMP);      // row is_global
        const int  sr = (li >= NCMP);                  // row segment
        float* orow = out + (size_t)(b * PERN + li) * PERN;

        // Lane owns j = c*256 + 4*lane + k: each f32x4 store is wave-contiguous
        // (64 lanes x 16B = 1KB aligned burst -> full 64B lines, L2 write-back).
#pragma unroll
        for (int c = 0; c < 2; ++c) {
            const int jbase = c * 256 + (lane << 2);
            f32x4 cc, ii, mm;
#pragma unroll
            for (int k = 0; k < 4; ++k) {
                const int j = jbase + k;
                const int slot = j ^ ((j >> 3) & 7);
                const float4 pj = pt[slot];
                const float dx = pi.x - pj.x;
                const float dy = pi.y - pj.y;
                const float dz = pi.z - pj.z;
                const float d2 = dx * dx + dy * dy + dz * dz;
                const bool valid = (j != li);
                const bool fin = valid & (d2 > 0.0f);      // dist finite in ref
                const float dist = __builtin_amdgcn_sqrtf(d2);
                const bool cgl = (j == 0) | (j == NCMP);   // col is_global (raw)
                const bool cg = cgl & valid;
                const bool notg = !(rg | cg);
                const int  sj = (j >= NCMP);
                const bool same = valid & (sr == sj);
                const bool ctxr  = same & (sr == 1) & notg & fin & (dist <= INTRA_CUT);
                const bool inter = valid & (sr != sj) & notg & fin & (dist <= INTER_CUT);
                const bool gnorm = same & (!notg);
                const bool gg    = valid & rg & cgl;
                const bool ctx   = ctxr | gnorm | gg;
                cc[k] = ctx ? 1.0f : 0.0f;
                ii[k] = inter ? 1.0f : 0.0f;
                mm[k] = ((ctx | inter) & fin) ? dist : 0.0f;
            }
            *reinterpret_cast<f32x4*>(orow + jbase)          = cc;
            *reinterpret_cast<f32x4*>(orow + NP + jbase)     = ii;
            *reinterpret_cast<f32x4*>(orow + 2 * NP + jbase) = mm;
        }
    }
}

extern "C" void kernel_launch(void* const* d_in, const int* in_sizes, int n_in,
                              void* d_out, int out_size, void* d_ws, size_t ws_size,
                              hipStream_t stream) {
    const float* X = (const float*)d_in[0];
    float* out = (float*)d_out;
    const int grid = BATCHES * (PERN / ROWS_PER_BLOCK);  // 2048 blocks
    pair_mask_kernel<<<grid, 256, 0, stream>>>(X, out);
}

// Round 7
// 33.268 us; speedup vs baseline: 4.0115x; 1.1040x over previous
//
#include <hip/hip_runtime.h>

// Problem constants (fixed by setup_inputs: B=64, PER=512, N_COMPOUND=112)
constexpr int PERN = 512;
constexpr int NCMP = 112;
constexpr int BATCHES = 64;
constexpr float INTRA_CUT = 1.6f;   // 8.0 / 5.0
constexpr float INTER_CUT = 2.0f;   // 10.0 / 5.0
constexpr int ROWS_PER_BLOCK = 16;  // 32 blocks per batch

typedef float f32x4 __attribute__((ext_vector_type(4)));

// 8 waves/EU -> VGPR capped at 64 -> full 32 waves/CU for store-latency hiding.
__global__ __launch_bounds__(256, 8) void pair_mask_kernel(
    const float* __restrict__ X, float* __restrict__ out)
{
    // SoA point tile: lane l reads xs[4l..4l+3] (one ds_read_b128 per
    // component) -> 1KB per wave-instruction, inherent 8-cycle minimum, no
    // pathological bank conflict, no swizzle address math.
    __shared__ float xs[PERN];
    __shared__ float ys[PERN];
    __shared__ float zs[PERN];

    const int tid = threadIdx.x;
    const int blk = blockIdx.x;
    const int b = blk / (PERN / ROWS_PER_BLOCK);
    const int row0 = (blk % (PERN / ROWS_PER_BLOCK)) * ROWS_PER_BLOCK;

    // Stage this batch's 512 points, transposed to SoA.
    const float* Xb = X + (size_t)b * PERN * 3;
    for (int p = tid; p < PERN; p += 256) {
        xs[p] = Xb[3 * p + 0];
        ys[p] = Xb[3 * p + 1];
        zs[p] = Xb[3 * p + 2];
    }
    __syncthreads();

    const int lane = tid & 63;   // lane within wave
    const int sub = tid >> 6;    // wave index in block
    const size_t NP = (size_t)BATCHES * PERN * PERN;  // elements per plane

    // Each wave owns 4 CONSECUTIVE rows (row0+4*sub .. +3): its store streams
    // advance monotonically in 2KB steps (8KB contiguous per plane per wave).
    for (int pass = 0; pass < ROWS_PER_BLOCK / 4; ++pass) {
        const int li = row0 + sub * 4 + pass;          // local row index
        const float pix = xs[li];                      // broadcast reads
        const float piy = ys[li];
        const float piz = zs[li];
        const bool rg = (li == 0) | (li == NCMP);      // row is_global
        const int  sr = (li >= NCMP);                  // row segment
        float* orow = out + (size_t)(b * PERN + li) * PERN;

        // Lane owns j = c*256 + 4*lane + k: each f32x4 store is wave-contiguous
        // (64 lanes x 16B = 1KB aligned burst -> full 64B lines, L2 write-back).
#pragma unroll
        for (int c = 0; c < 2; ++c) {
            const int jbase = c * 256 + (lane << 2);
            const f32x4 xv = *reinterpret_cast<const f32x4*>(&xs[jbase]);
            const f32x4 yv = *reinterpret_cast<const f32x4*>(&ys[jbase]);
            const f32x4 zv = *reinterpret_cast<const f32x4*>(&zs[jbase]);
            f32x4 cc, ii, mm;
#pragma unroll
            for (int k = 0; k < 4; ++k) {
                const int j = jbase + k;
                const float dx = pix - xv[k];
                const float dy = piy - yv[k];
                const float dz = piz - zv[k];
                const float d2 = dx * dx + dy * dy + dz * dz;
                const bool valid = (j != li);
                const bool fin = valid & (d2 > 0.0f);      // dist finite in ref
                const float dist = __builtin_amdgcn_sqrtf(d2);
                const bool cgl = (j == 0) | (j == NCMP);   // col is_global (raw)
                const bool cg = cgl & valid;
                const bool notg = !(rg | cg);
                const int  sj = (j >= NCMP);
                const bool same = valid & (sr == sj);
                const bool ctxr  = same & (sr == 1) & notg & fin & (dist <= INTRA_CUT);
                const bool inter = valid & (sr != sj) & notg & fin & (dist <= INTER_CUT);
                const bool gnorm = same & (!notg);
                const bool gg    = valid & rg & cgl;
                const bool ctx   = ctxr | gnorm | gg;
                cc[k] = ctx ? 1.0f : 0.0f;
                ii[k] = inter ? 1.0f : 0.0f;
                mm[k] = ((ctx | inter) & fin) ? dist : 0.0f;
            }
            *reinterpret_cast<f32x4*>(orow + jbase)          = cc;
            *reinterpret_cast<f32x4*>(orow + NP + jbase)     = ii;
            *reinterpret_cast<f32x4*>(orow + 2 * NP + jbase) = mm;
        }
    }
}

extern "C" void kernel_launch(void* const* d_in, const int* in_sizes, int n_in,
                              void* d_out, int out_size, void* d_ws, size_t ws_size,
                              hipStream_t stream) {
    const float* X = (const float*)d_in[0];
    float* out = (float*)d_out;
    const int grid = BATCHES * (PERN / ROWS_PER_BLOCK);  // 2048 blocks
    pair_mask_kernel<<<grid, 256, 0, stream>>>(X, out);
}